// Round 1
// baseline (83.855 us; speedup 1.0000x reference)
//
#include <hip/hip_runtime.h>

// Problem: SpatialTransform
//   x:     (16, 256, 256, 32) f32
//   W_loc: (32, 6) f32
//   b_loc: (6) f32
//   out:   (16, 256, 256, 32) f32
//
// out = bilinear_sample(x, affine_grid(theta)), theta = mean_pool(x) @ W_loc + b_loc

#define NIMG 16
#define HDIM 256
#define WDIM 256
#define CH   32
#define HW   (HDIM * WDIM)

#define BLOCKS_PER_IMG 128   // sum kernel blocks per image

// ---------------------------------------------------------------------------
// Kernel 1: per-(n,c) sum over H*W.  256 threads/block: 8 thread-groups of
// float4 cover the 32 channels; 32 spatial positions per iteration.
// ---------------------------------------------------------------------------
__global__ __launch_bounds__(256) void st_sum_kernel(
    const float* __restrict__ x, float* __restrict__ sums) {
    const int n   = blockIdx.x / BLOCKS_PER_IMG;
    const int blk = blockIdx.x % BLOCKS_PER_IMG;
    const int tid = threadIdx.x;
    const int cg  = tid & 7;    // channel group of 4 (float4)
    const int sp  = tid >> 3;   // spatial slot 0..31

    const float4* xp = (const float4*)(x + (size_t)n * HW * CH);
    float4 acc = make_float4(0.f, 0.f, 0.f, 0.f);
    for (int s = blk * 32 + sp; s < HW; s += BLOCKS_PER_IMG * 32) {
        float4 v = xp[(size_t)s * 8 + cg];
        acc.x += v.x; acc.y += v.y; acc.z += v.z; acc.w += v.w;
    }

    __shared__ float4 red[256];
    red[tid] = acc;
    __syncthreads();
    for (int stride = 16; stride >= 1; stride >>= 1) {
        if (sp < stride) {
            float4 o = red[(sp + stride) * 8 + cg];
            acc.x += o.x; acc.y += o.y; acc.z += o.z; acc.w += o.w;
            red[tid] = acc;
        }
        __syncthreads();
    }
    if (sp == 0) {
        float* s4 = sums + n * CH + cg * 4;
        atomicAdd(s4 + 0, acc.x);
        atomicAdd(s4 + 1, acc.y);
        atomicAdd(s4 + 2, acc.z);
        atomicAdd(s4 + 3, acc.w);
    }
}

// ---------------------------------------------------------------------------
// Kernel 2: theta[n][k] = sum_c mean[n][c] * W_loc[c][k] + b_loc[k]
// 96 threads, one per (n,k).
// ---------------------------------------------------------------------------
__global__ void st_theta_kernel(const float* __restrict__ sums,
                                const float* __restrict__ W_loc,
                                const float* __restrict__ b_loc,
                                float* __restrict__ theta) {
    int i = threadIdx.x;
    if (i >= NIMG * 6) return;
    int n = i / 6, k = i % 6;
    float acc = b_loc[k];
    const float inv = 1.0f / (float)HW;
    for (int c = 0; c < CH; ++c) {
        acc = fmaf(sums[n * CH + c] * inv, W_loc[c * 6 + k], acc);
    }
    theta[i] = acc;
}

// ---------------------------------------------------------------------------
// Kernel 3: bilinear gather.  One block = (n, ho, 32 consecutive wo).
// 8 threads (float4) per output pixel -> 128B coalesced per pixel.
// ---------------------------------------------------------------------------
__global__ __launch_bounds__(256) void st_interp_kernel(
    const float* __restrict__ x, const float* __restrict__ theta,
    float* __restrict__ out) {
    const int bid = blockIdx.x;
    const int tid = threadIdx.x;
    const int n   = bid >> 11;          // 2048 blocks per image
    const int r   = bid & 2047;
    const int ho  = r >> 3;             // 8 blocks per row
    const int wo  = ((r & 7) << 5) + (tid >> 3);
    const int cg  = tid & 7;

    const float* th = theta + n * 6;
    const float t00 = th[0], t01 = th[1], t02 = th[2];
    const float t10 = th[3], t11 = th[4], t12 = th[5];

    const float gy = fmaf((float)ho, 2.0f / 255.0f, -1.0f);
    const float gx = fmaf((float)wo, 2.0f / 255.0f, -1.0f);

    // coords -> pixel coords: up = (theta·[gy,gx,1] + 1) * (255/2)
    const float uy = (fmaf(t00, gy, fmaf(t01, gx, t02)) + 1.0f) * 127.5f;
    const float ux = (fmaf(t10, gy, fmaf(t11, gx, t12)) + 1.0f) * 127.5f;

    const float fy = floorf(uy), fx = floorf(ux);
    const float ry = uy - fy, rx = ux - fx;
    const int iy = (int)fy, ix = (int)fx;
    const int iy0 = min(max(iy,     0), HDIM - 1);
    const int iy1 = min(max(iy + 1, 0), HDIM - 1);
    const int ix0 = min(max(ix,     0), WDIM - 1);
    const int ix1 = min(max(ix + 1, 0), WDIM - 1);

    const float4* xp = (const float4*)(x + (size_t)n * HW * CH);
    float4 v00 = xp[(size_t)(iy0 * WDIM + ix0) * 8 + cg];
    float4 v01 = xp[(size_t)(iy0 * WDIM + ix1) * 8 + cg];
    float4 v10 = xp[(size_t)(iy1 * WDIM + ix0) * 8 + cg];
    float4 v11 = xp[(size_t)(iy1 * WDIM + ix1) * 8 + cg];

    const float w00 = (1.0f - ry) * (1.0f - rx);
    const float w01 = (1.0f - ry) * rx;
    const float w10 = ry * (1.0f - rx);
    const float w11 = ry * rx;

    float4 o;
    o.x = v00.x * w00 + v01.x * w01 + v10.x * w10 + v11.x * w11;
    o.y = v00.y * w00 + v01.y * w01 + v10.y * w10 + v11.y * w11;
    o.z = v00.z * w00 + v01.z * w01 + v10.z * w10 + v11.z * w11;
    o.w = v00.w * w00 + v01.w * w01 + v10.w * w10 + v11.w * w11;

    float4* op = (float4*)(out + (size_t)n * HW * CH);
    op[(size_t)(ho * WDIM + wo) * 8 + cg] = o;
}

extern "C" void kernel_launch(void* const* d_in, const int* in_sizes, int n_in,
                              void* d_out, int out_size, void* d_ws, size_t ws_size,
                              hipStream_t stream) {
    const float* x     = (const float*)d_in[0];
    const float* W_loc = (const float*)d_in[1];
    const float* b_loc = (const float*)d_in[2];
    float* out = (float*)d_out;

    // workspace layout: sums[16*32] f32, theta[16*6] f32
    float* sums  = (float*)d_ws;
    float* theta = sums + NIMG * CH;

    // zero the accumulators (harness does NOT re-zero between replays)
    hipMemsetAsync(sums, 0, NIMG * CH * sizeof(float), stream);

    st_sum_kernel<<<NIMG * BLOCKS_PER_IMG, 256, 0, stream>>>(x, sums);
    st_theta_kernel<<<1, 128, 0, stream>>>(sums, W_loc, b_loc, theta);
    st_interp_kernel<<<NIMG * (HW / 32), 256, 0, stream>>>(x, theta, out);
}

// Round 2
// 75.637 us; speedup vs baseline: 1.1086x; 1.1086x over previous
//
#include <hip/hip_runtime.h>

// Problem: SpatialTransform
//   x:     (16, 256, 256, 32) f32
//   W_loc: (32, 6) f32
//   b_loc: (6) f32
//   out:   (16, 256, 256, 32) f32
//
// out = bilinear_sample(x, affine_grid(theta)), theta = mean_pool(x) @ W_loc + b_loc

#define NIMG 16
#define HDIM 256
#define WDIM 256
#define CH   32
#define HW   (HDIM * WDIM)
#define BPI  128   // sum-kernel blocks per image

typedef float f32x4 __attribute__((ext_vector_type(4)));

// ---------------------------------------------------------------------------
// Kernel 1: per-(n,c) partial sums, one partial vector per block (no atomics).
// partials layout: [BPI][NIMG][CH]
// ---------------------------------------------------------------------------
__global__ __launch_bounds__(256) void st_sum_kernel(
    const float* __restrict__ x, float* __restrict__ partials) {
    const int n   = blockIdx.x / BPI;
    const int blk = blockIdx.x % BPI;
    const int tid = threadIdx.x;
    const int cg  = tid & 7;    // channel group of 4 (float4)
    const int sp  = tid >> 3;   // spatial slot 0..31

    const float4* xp = (const float4*)(x + (size_t)n * HW * CH);
    float4 acc = make_float4(0.f, 0.f, 0.f, 0.f);
    for (int s = blk * 32 + sp; s < HW; s += BPI * 32) {
        float4 v = xp[(size_t)s * 8 + cg];
        acc.x += v.x; acc.y += v.y; acc.z += v.z; acc.w += v.w;
    }

    __shared__ float4 red[256];
    red[tid] = acc;
    __syncthreads();
    for (int stride = 16; stride >= 1; stride >>= 1) {
        if (sp < stride) {
            float4 o = red[(sp + stride) * 8 + cg];
            acc.x += o.x; acc.y += o.y; acc.z += o.z; acc.w += o.w;
            red[tid] = acc;
        }
        __syncthreads();
    }
    if (sp == 0) {
        ((float4*)(partials + ((size_t)blk * NIMG + n) * CH))[cg] = acc;
    }
}

// ---------------------------------------------------------------------------
// Kernel 2: reduce partials -> means, then theta[n][k].
// 512 threads = one per (n,c); first 96 compute theta.
// ---------------------------------------------------------------------------
__global__ __launch_bounds__(512) void st_theta_kernel(
    const float* __restrict__ partials, const float* __restrict__ W_loc,
    const float* __restrict__ b_loc, float* __restrict__ theta) {
    __shared__ float mean[NIMG * CH];
    const int t = threadIdx.x;  // 0..511 = n*32+c
    float s = 0.f;
    for (int b = 0; b < BPI; ++b) s += partials[b * NIMG * CH + t];
    mean[t] = s * (1.0f / (float)HW);
    __syncthreads();
    if (t < NIMG * 6) {
        const int n = t / 6, k = t % 6;
        float acc = b_loc[k];
        for (int c = 0; c < CH; ++c)
            acc = fmaf(mean[n * CH + c], W_loc[c * 6 + k], acc);
        theta[t] = acc;
    }
}

// ---------------------------------------------------------------------------
// Kernel 3: bilinear gather.  One block = 4x8 pixel tile (32 px, 8 thr/px).
// XCD-aware swizzle: 32768 blocks % 8 == 0; each XCD owns 2 whole images.
// Nontemporal output stores keep x resident in L3.
// ---------------------------------------------------------------------------
__global__ __launch_bounds__(256) void st_interp_kernel(
    const float* __restrict__ x, const float* __restrict__ theta,
    float* __restrict__ out) {
    const int bid = (int)blockIdx.x;
    const int swz = (bid & 7) * 4096 + (bid >> 3);  // 8 XCDs, 4096 blocks each
    const int n   = swz >> 11;                      // 2048 tiles per image
    const int r   = swz & 2047;
    const int ty  = r >> 5;                         // 64 tile-rows
    const int tx  = r & 31;                         // 32 tile-cols
    const int tid = threadIdx.x;
    const int p   = tid >> 3;                       // pixel 0..31 in tile
    const int cg  = tid & 7;                        // float4 channel group
    const int ho  = ty * 4 + (p >> 3);
    const int wo  = tx * 8 + (p & 7);

    const float* th = theta + n * 6;
    const float t00 = th[0], t01 = th[1], t02 = th[2];
    const float t10 = th[3], t11 = th[4], t12 = th[5];

    const float gy = fmaf((float)ho, 2.0f / 255.0f, -1.0f);
    const float gx = fmaf((float)wo, 2.0f / 255.0f, -1.0f);

    const float uy = (fmaf(t00, gy, fmaf(t01, gx, t02)) + 1.0f) * 127.5f;
    const float ux = (fmaf(t10, gy, fmaf(t11, gx, t12)) + 1.0f) * 127.5f;

    const float fy = floorf(uy), fx = floorf(ux);
    const float ry = uy - fy, rx = ux - fx;
    const int iy = (int)fy, ix = (int)fx;
    const int iy0 = min(max(iy,     0), HDIM - 1);
    const int iy1 = min(max(iy + 1, 0), HDIM - 1);
    const int ix0 = min(max(ix,     0), WDIM - 1);
    const int ix1 = min(max(ix + 1, 0), WDIM - 1);

    const float4* xp = (const float4*)(x + (size_t)n * HW * CH);
    float4 v00 = xp[(size_t)(iy0 * WDIM + ix0) * 8 + cg];
    float4 v01 = xp[(size_t)(iy0 * WDIM + ix1) * 8 + cg];
    float4 v10 = xp[(size_t)(iy1 * WDIM + ix0) * 8 + cg];
    float4 v11 = xp[(size_t)(iy1 * WDIM + ix1) * 8 + cg];

    const float w00 = (1.0f - ry) * (1.0f - rx);
    const float w01 = (1.0f - ry) * rx;
    const float w10 = ry * (1.0f - rx);
    const float w11 = ry * rx;

    f32x4 o;
    o.x = v00.x * w00 + v01.x * w01 + v10.x * w10 + v11.x * w11;
    o.y = v00.y * w00 + v01.y * w01 + v10.y * w10 + v11.y * w11;
    o.z = v00.z * w00 + v01.z * w01 + v10.z * w10 + v11.z * w11;
    o.w = v00.w * w00 + v01.w * w01 + v10.w * w10 + v11.w * w11;

    f32x4* op = (f32x4*)(out + (size_t)n * HW * CH);
    __builtin_nontemporal_store(o, &op[(size_t)(ho * WDIM + wo) * 8 + cg]);
}

extern "C" void kernel_launch(void* const* d_in, const int* in_sizes, int n_in,
                              void* d_out, int out_size, void* d_ws, size_t ws_size,
                              hipStream_t stream) {
    const float* x     = (const float*)d_in[0];
    const float* W_loc = (const float*)d_in[1];
    const float* b_loc = (const float*)d_in[2];
    float* out = (float*)d_out;

    // workspace layout: partials[BPI*NIMG*CH] f32, theta[16*6] f32
    float* partials = (float*)d_ws;
    float* theta    = partials + BPI * NIMG * CH;

    st_sum_kernel<<<NIMG * BPI, 256, 0, stream>>>(x, partials);
    st_theta_kernel<<<1, 512, 0, stream>>>(partials, W_loc, b_loc, theta);
    st_interp_kernel<<<NIMG * (HW / 32), 256, 0, stream>>>(x, theta, out);
}